// Round 1
// baseline (5328.222 us; speedup 1.0000x reference)
//
#include <hip/hip_runtime.h>
#include <hip/hip_bf16.h>

// ---------------------------------------------------------------------------
// Sophie trajectory model on MI355X.
// Key fusion: per step, one bf16 MFMA GEMM computes
//   Z = A @ [w_hh.T | wk.T | wv.T | wq.T]   (A = [ho(4096); ht(1); pad(127)])
// giving next-step LSTM gates, k, v, q in a single launch.
// ---------------------------------------------------------------------------

typedef __bf16 bf16x8 __attribute__((ext_vector_type(8)));
typedef float  f32x4  __attribute__((ext_vector_type(4)));

#define MROWS 4224      // 4096 others + 1 target + 127 pad
#define NCOLS 3584      // 2048 gates | 512 k | 512 v | 512 q
#define KDIM  512

__device__ __forceinline__ void gl_lds16(const void* g, void* l) {
  __builtin_amdgcn_global_load_lds(
      (const __attribute__((address_space(1))) void*)g,
      (__attribute__((address_space(3))) void*)l, 16, 0, 0);
}

__device__ __forceinline__ float sigm(float x) {
  return 1.0f / (1.0f + expf(-x));
}

__device__ __forceinline__ __bf16 to_bf16(float f) { return (__bf16)f; }

// ---------------------------------------------------------------------------
// GEMM: Z[MROWS][NCOLS] = A[MROWS][512](bf16) @ Wp(packed bf16)
// Wp layout: [N/16][K/8][16 n][8 k] so B-fragments are lane-contiguous 16B.
// Block: 256 thr (4 waves), 128x128 tile, BK=64, mfma 16x16x32 bf16.
// Block list pruned: bn 0..15 -> bm 0..32 ; bn 16..23 -> bm 0..31 ; bn 24..27 -> bm 32.
// Total blocks = 33*16 + 32*8 + 4 = 788.
// ---------------------------------------------------------------------------
__global__ __launch_bounds__(256) void gemm_kernel(
    const unsigned short* __restrict__ A,   // [4224][512] bf16 bits
    const unsigned short* __restrict__ Wp,  // packed
    float* __restrict__ Z)
{
  __shared__ __align__(16) char aLds[128 * 64 * 2];        // 16 KB (xor-swizzled)
  __shared__ __align__(16) char bLds[8 * 8 * 16 * 8 * 2];  // 16 KB [nt][kg][nn][j]

  const int tid  = threadIdx.x;
  const int wave = tid >> 6;
  const int lane = tid & 63;

  int id = blockIdx.x;
  int bm, bn;
  if (id < 528)      { bn = id / 33;              bm = id % 33; }
  else if (id < 784) { int t2 = id - 528; bn = 16 + (t2 >> 5); bm = t2 & 31; }
  else               { bm = 32;                   bn = 24 + (id - 784); }

  const int m0 = bm * 128;
  const int n0 = bn * 128;
  const int ntg0 = n0 >> 4;

  const int wm = wave >> 1, wn = wave & 1;

  // staging descriptors (4 chunks of 1KB per wave for each of A and B)
  int aRow[4], aChg[4], ldsOff[4];
  const unsigned short* gbBase[4];
#pragma unroll
  for (int j = 0; j < 4; ++j) {
    int chunk = j * 4 + wave;
    int r  = chunk * 8 + (lane >> 3);
    int ch = lane & 7;
    aRow[j]   = m0 + r;
    aChg[j]   = (ch ^ (r & 7)) * 8;     // element offset inside row
    ldsOff[j] = chunk * 1024;
    int nt = chunk >> 1, half = chunk & 1;
    gbBase[j] = Wp + (ntg0 + nt) * 64 * 128 + half * 512 + lane * 8;
  }

  f32x4 acc[4][4];
#pragma unroll
  for (int i = 0; i < 4; ++i)
#pragma unroll
    for (int j = 0; j < 4; ++j) acc[i][j] = f32x4{0.f, 0.f, 0.f, 0.f};

  for (int k0 = 0; k0 < KDIM; k0 += 64) {
#pragma unroll
    for (int j = 0; j < 4; ++j) {
      gl_lds16(A + aRow[j] * KDIM + k0 + aChg[j], aLds + ldsOff[j]);
      gl_lds16(gbBase[j] + k0 * 16, bLds + ldsOff[j]);
    }
    __syncthreads();   // drains vmcnt (incl. global_load_lds) before barrier

#pragma unroll
    for (int c = 0; c < 2; ++c) {
      bf16x8 af[4], bf[4];
#pragma unroll
      for (int mt = 0; mt < 4; ++mt) {
        int row = wm * 64 + mt * 16 + (lane & 15);
        int ch16 = (c * 4 + (lane >> 4)) ^ (row & 7);
        af[mt] = *(const bf16x8*)(aLds + row * 128 + ch16 * 16);
      }
#pragma unroll
      for (int nt = 0; nt < 4; ++nt) {
        bf[nt] = *(const bf16x8*)(bLds + (((wn * 4 + nt) * 128 + c * 64 + lane) << 4));
      }
#pragma unroll
      for (int mt = 0; mt < 4; ++mt)
#pragma unroll
        for (int nt = 0; nt < 4; ++nt)
          acc[mt][nt] = __builtin_amdgcn_mfma_f32_16x16x32_bf16(
              af[mt], bf[nt], acc[mt][nt], 0, 0, 0);
    }
    __syncthreads();
  }

  // epilogue: D row = quad*4+reg (M), col = lane&15 (N)
  const int rq = (lane >> 4) * 4;
  const int cl = lane & 15;
#pragma unroll
  for (int mt = 0; mt < 4; ++mt)
#pragma unroll
    for (int nt = 0; nt < 4; ++nt) {
      int colg = n0 + wn * 64 + nt * 16 + cl;
#pragma unroll
      for (int r = 0; r < 4; ++r) {
        int rowg = m0 + wm * 64 + mt * 16 + rq + r;
        Z[rowg * NCOLS + colg] = acc[mt][nt][r];
      }
    }
}

// ---------------------------------------------------------------------------
// LSTM elementwise update (others rows 0..4095 + target branch block 8192).
// gates(n) = Z[r][n]*use_z + b_ih[n] + b_hh[n] + w_ih[n][0]*x0 + w_ih[n][1]*x1
// ---------------------------------------------------------------------------
__global__ __launch_bounds__(256) void update_kernel(
    const float* __restrict__ Z,
    const float* __restrict__ op,    // others[min(t,31)] base: [4096][2]
    const float* __restrict__ tp,    // target[t]: 2 floats
    const float* __restrict__ w_ih,  // [2048][2]
    const float* __restrict__ b_ih,
    const float* __restrict__ b_hh,
    float* __restrict__ co,          // [4096*512]
    float* __restrict__ ct_t,        // [512]
    float* __restrict__ ht_f32,      // [512]
    __bf16* __restrict__ A,          // [4224][512]
    int use_z)
{
  int b = blockIdx.x;
  if (b < 8192) {
    int g = b * 256 + threadIdx.x;
    int r = g >> 9, j = g & 511;
    float x0 = op[2 * r], x1 = op[2 * r + 1];
    float pre[4];
#pragma unroll
    for (int gg = 0; gg < 4; ++gg) {
      int n = gg * 512 + j;
      float p = b_ih[n] + b_hh[n] + w_ih[2 * n] * x0 + w_ih[2 * n + 1] * x1;
      if (use_z) p += Z[r * NCOLS + n];
      pre[gg] = p;
    }
    float c_old = use_z ? co[g] : 0.f;
    float ii = sigm(pre[0]), ff = sigm(pre[1]);
    float gg2 = tanhf(pre[2]), oo = sigm(pre[3]);
    float cn = ff * c_old + ii * gg2;
    float h = oo * tanhf(cn);
    co[g] = cn;
    A[r * 512 + j] = to_bf16(h);
  } else {
    float x0 = tp[0], x1 = tp[1];
    for (int j = threadIdx.x; j < 512; j += 256) {
      float pre[4];
#pragma unroll
      for (int gg = 0; gg < 4; ++gg) {
        int n = gg * 512 + j;
        float p = b_ih[n] + b_hh[n] + w_ih[2 * n] * x0 + w_ih[2 * n + 1] * x1;
        if (use_z) p += Z[4096 * NCOLS + n];
        pre[gg] = p;
      }
      float c_old = use_z ? ct_t[j] : 0.f;
      float ii = sigm(pre[0]), ff = sigm(pre[1]);
      float gg2 = tanhf(pre[2]), oo = sigm(pre[3]);
      float cn = ff * c_old + ii * gg2;
      float h = oo * tanhf(cn);
      ct_t[j] = cn;
      ht_f32[j] = h;
      A[4096 * 512 + j] = to_bf16(h);
    }
  }
}

// ---------------------------------------------------------------------------
// Attention partials: 64 blocks x 64 rows. e_r = exp(q.k_r / sqrt(512));
// partial[b] = {sum_r e_r * v_r[0..511], sum_r e_r}. Logits bounded (~|x|<1),
// so exp without max-subtraction is safe.
// ---------------------------------------------------------------------------
__global__ __launch_bounds__(256) void att_kernel(
    const float* __restrict__ Z,
    const float* __restrict__ bq,
    const float* __restrict__ bk,
    const float* __restrict__ bv,
    float* __restrict__ partial)     // [64][513]
{
  __shared__ float qs[512];
  __shared__ float red[256];
  __shared__ float es[64];
  const int b = blockIdx.x, t = threadIdx.x;

  for (int c = t; c < 512; c += 256)
    qs[c] = Z[4096 * NCOLS + 3072 + c] + bq[c];
  __syncthreads();

  const int r0 = b * 64;
  const int rl = t >> 2, p = t & 3;
  const float* krow = Z + (r0 + rl) * NCOLS + 2048;
  float acc = 0.f;
  for (int i = p; i < 512; i += 4) acc += (krow[i] + bk[i]) * qs[i];
  red[t] = acc;
  __syncthreads();
  if (t < 64) {
    float l = red[4 * t] + red[4 * t + 1] + red[4 * t + 2] + red[4 * t + 3];
    es[t] = expf(l * 0.04419417382415922f);   // 1/sqrt(512)
  }
  __syncthreads();

  float s0 = 0.f, s1 = 0.f;
  for (int r = 0; r < 64; ++r) {
    const float* vrow = Z + (r0 + r) * NCOLS + 2560;
    float e = es[r];
    s0 += e * (vrow[t] + bv[t]);
    s1 += e * (vrow[t + 256] + bv[t + 256]);
  }
  partial[b * 513 + t] = s0;
  partial[b * 513 + t + 256] = s1;
  if (t == 0) {
    float se = 0.f;
    for (int r = 0; r < 64; ++r) se += es[r];
    partial[b * 513 + 512] = se;
  }
}

// ---------------------------------------------------------------------------
// Finalize: social = sum(partials)/sum(e); out = (ht+social+scene)@out_w.T+out_b
// ---------------------------------------------------------------------------
__global__ __launch_bounds__(512) void finalize_kernel(
    const float* __restrict__ partial,
    const float* __restrict__ ht,
    const float* __restrict__ scene,
    const float* __restrict__ out_w,  // [2][512]
    const float* __restrict__ out_b,
    float* __restrict__ out, int tstep)
{
  __shared__ float r0[512], r1[512];
  const int j = threadIdx.x;
  float s = 0.f, se = 0.f;
  for (int b = 0; b < 64; ++b) {
    s += partial[b * 513 + j];
    se += partial[b * 513 + 512];
  }
  float social = s / se;
  float val = ht[j] + social + scene[j];
  r0[j] = val * out_w[j];
  r1[j] = val * out_w[512 + j];
  __syncthreads();
  for (int st = 256; st > 0; st >>= 1) {
    if (j < st) { r0[j] += r0[j + st]; r1[j] += r1[j + st]; }
    __syncthreads();
  }
  if (j == 0) {
    out[2 * tstep]     = r0[0] + out_b[0];
    out[2 * tstep + 1] = r1[0] + out_b[1];
  }
}

// ---------------------------------------------------------------------------
// Scene CNN (run once per call; cheap).
// ---------------------------------------------------------------------------
__global__ __launch_bounds__(256) void scene1_kernel(
    const int* __restrict__ map, const float* __restrict__ emb,
    const float* __restrict__ w1, const float* __restrict__ b1,
    float* __restrict__ out1)   // [16][256][256]
{
  __shared__ float wl[576];
  __shared__ float bl[16];
  const int t = threadIdx.x;
  for (int i = t; i < 576; i += 256) wl[i] = w1[i];
  if (t < 16) bl[t] = b1[t];
  __syncthreads();
  const int y = blockIdx.x, x = t;
  float nb[4][9];
#pragma unroll
  for (int dy = 0; dy < 3; ++dy)
#pragma unroll
    for (int dx = 0; dx < 3; ++dx) {
      int yy = y + dy - 1, xx = x + dx - 1;
      bool ok = (yy >= 0 && yy < 256 && xx >= 0 && xx < 256);
      int m = ok ? map[yy * 256 + xx] : 0;
#pragma unroll
      for (int c = 0; c < 4; ++c)
        nb[c][dy * 3 + dx] = ok ? emb[m * 4 + c] : 0.f;
    }
  for (int oc = 0; oc < 16; ++oc) {
    float a = bl[oc];
#pragma unroll
    for (int c = 0; c < 4; ++c)
#pragma unroll
      for (int k = 0; k < 9; ++k) a += wl[(oc * 4 + c) * 9 + k] * nb[c][k];
    out1[oc * 65536 + y * 256 + x] = fmaxf(a, 0.f);
  }
}

__global__ __launch_bounds__(256) void scene2_kernel(
    const float* __restrict__ out1, const float* __restrict__ w2,
    const float* __restrict__ b2, float* __restrict__ rowpart)  // [256][32]
{
  __shared__ float wl[4608];
  __shared__ float lds4[4 * 32];
  const int t = threadIdx.x;
  for (int i = t; i < 4608; i += 256) wl[i] = w2[i];
  __syncthreads();
  const int y = blockIdx.x, x = t;
  float acc[32];
#pragma unroll
  for (int oc = 0; oc < 32; ++oc) acc[oc] = b2[oc];
  for (int ic = 0; ic < 16; ++ic) {
    float nb[9];
#pragma unroll
    for (int dy = 0; dy < 3; ++dy)
#pragma unroll
      for (int dx = 0; dx < 3; ++dx) {
        int yy = y + dy - 1, xx = x + dx - 1;
        bool ok = (yy >= 0 && yy < 256 && xx >= 0 && xx < 256);
        nb[dy * 3 + dx] = ok ? out1[ic * 65536 + yy * 256 + xx] : 0.f;
      }
    for (int oc = 0; oc < 32; ++oc) {
      const float* w = &wl[(oc * 16 + ic) * 9];
#pragma unroll
      for (int k = 0; k < 9; ++k) acc[oc] += w[k] * nb[k];
    }
  }
  const int wave = t >> 6, lane = t & 63;
  for (int oc = 0; oc < 32; ++oc) {
    float v = fmaxf(acc[oc], 0.f);
#pragma unroll
    for (int m = 1; m < 64; m <<= 1) v += __shfl_xor(v, m, 64);
    if (lane == 0) lds4[wave * 32 + oc] = v;
  }
  __syncthreads();
  if (t < 32)
    rowpart[y * 32 + t] = lds4[t] + lds4[32 + t] + lds4[64 + t] + lds4[96 + t];
}

__global__ __launch_bounds__(512) void scene3_kernel(
    const float* __restrict__ rowpart, const float* __restrict__ fcw,
    const float* __restrict__ fcb, float* __restrict__ scene)
{
  __shared__ float mean[32];
  const int t = threadIdx.x;
  if (t < 32) {
    float s = 0.f;
    for (int y = 0; y < 256; ++y) s += rowpart[y * 32 + t];
    mean[t] = s * (1.f / 65536.f);
  }
  __syncthreads();
  float a = fcb[t];
#pragma unroll
  for (int c = 0; c < 32; ++c) a += mean[c] * fcw[t * 32 + c];
  scene[t] = a;
}

// ---------------------------------------------------------------------------
// Pack weights fp32 -> bf16, layout [N/16][K/8][16][8].
// ---------------------------------------------------------------------------
__global__ __launch_bounds__(256) void pack_kernel(
    const float* __restrict__ w_hh, const float* __restrict__ wk,
    const float* __restrict__ wv,   const float* __restrict__ wq,
    __bf16* __restrict__ Wp)
{
  int o = blockIdx.x * 256 + threadIdx.x;  // exactly 512*3584 elements
  int j = o & 7, nn = (o >> 3) & 15, kg = (o >> 7) & 63, ntg = o >> 13;
  int n = ntg * 16 + nn, k = kg * 8 + j;
  float v;
  if (n < 2048)      v = w_hh[n * 512 + k];
  else if (n < 2560) v = wk[(n - 2048) * 512 + k];
  else if (n < 3072) v = wv[(n - 2560) * 512 + k];
  else               v = wq[(n - 3072) * 512 + k];
  Wp[o] = to_bf16(v);
}

__global__ __launch_bounds__(256) void zeroA_kernel(__bf16* __restrict__ A) {
  int i = blockIdx.x * 256 + threadIdx.x;
  if (i < 127 * 512) A[4097 * 512 + i] = to_bf16(0.f);
}

// ---------------------------------------------------------------------------
extern "C" void kernel_launch(void* const* d_in, const int* in_sizes, int n_in,
                              void* d_out, int out_size, void* d_ws, size_t ws_size,
                              hipStream_t stream) {
  const float* target    = (const float*)d_in[0];   // (64,1,2)
  const float* others    = (const float*)d_in[1];   // (32,4096,2)
  const int*   scene_map = (const int*)d_in[2];     // (256,256)
  const float* emb       = (const float*)d_in[3];   // (10,4)
  const float* c1w       = (const float*)d_in[4];
  const float* c1b       = (const float*)d_in[5];
  const float* c2w       = (const float*)d_in[6];
  const float* c2b       = (const float*)d_in[7];
  const float* fcw       = (const float*)d_in[8];
  const float* fcb       = (const float*)d_in[9];
  const float* w_ih      = (const float*)d_in[10];
  const float* w_hh      = (const float*)d_in[11];
  const float* b_ih      = (const float*)d_in[12];
  const float* b_hh      = (const float*)d_in[13];
  const float* wq        = (const float*)d_in[14];
  const float* bq        = (const float*)d_in[15];
  const float* wk        = (const float*)d_in[16];
  const float* bk        = (const float*)d_in[17];
  const float* wv        = (const float*)d_in[18];
  const float* bv        = (const float*)d_in[19];
  const float* out_w     = (const float*)d_in[20];
  const float* out_b     = (const float*)d_in[21];
  float* out = (float*)d_out;

  char* ws = (char*)d_ws;
  constexpr size_t OFF_Z     = 0;                         // 4224*3584*4 = 60555264
  constexpr size_t OFF_WP    = 60555264;                  // 512*3584*2  = 3670016
  constexpr size_t OFF_A     = OFF_WP + 3670016;          // 4224*512*2  = 4325376
  constexpr size_t OFF_CO    = OFF_A + 4325376;           // 8388608
  constexpr size_t OFF_CTT   = OFF_CO + 8388608;          // 2048
  constexpr size_t OFF_HT    = OFF_CTT + 2048;            // 2048
  constexpr size_t OFF_SCENE = OFF_HT + 2048;             // 2048
  constexpr size_t OFF_PART  = OFF_SCENE + 2048;          // 64*513*4 = 131328
  constexpr size_t OFF_OUT1  = OFF_PART + 131328;         // 16*65536*4 = 4194304
  constexpr size_t OFF_ROWP  = OFF_OUT1 + 4194304;        // 256*32*4 = 32768

  float*  Z      = (float*)(ws + OFF_Z);
  __bf16* Wp     = (__bf16*)(ws + OFF_WP);
  __bf16* A      = (__bf16*)(ws + OFF_A);
  float*  co     = (float*)(ws + OFF_CO);
  float*  ct_t   = (float*)(ws + OFF_CTT);
  float*  ht     = (float*)(ws + OFF_HT);
  float*  scene  = (float*)(ws + OFF_SCENE);
  float*  part   = (float*)(ws + OFF_PART);
  float*  out1   = (float*)(ws + OFF_OUT1);
  float*  rowp   = (float*)(ws + OFF_ROWP);

  // one-time prep
  pack_kernel<<<7168, 256, 0, stream>>>(w_hh, wk, wv, wq, Wp);
  zeroA_kernel<<<254, 256, 0, stream>>>(A);
  scene1_kernel<<<256, 256, 0, stream>>>(scene_map, emb, c1w, c1b, out1);
  scene2_kernel<<<256, 256, 0, stream>>>(out1, c2w, c2b, rowp);
  scene3_kernel<<<1, 512, 0, stream>>>(rowp, fcw, fcb, scene);

  // initial state: apply cell with zero h,c to inputs at t=0
  update_kernel<<<8193, 256, 0, stream>>>(Z, others, target, w_ih, b_ih, b_hh,
                                          co, ct_t, ht, A, 0);

  const unsigned short* Au  = (const unsigned short*)A;
  const unsigned short* Wpu = (const unsigned short*)Wp;

  for (int t = 0; t < 64; ++t) {
    gemm_kernel<<<788, 256, 0, stream>>>(Au, Wpu, Z);
    att_kernel<<<64, 256, 0, stream>>>(Z, bq, bk, bv, part);
    finalize_kernel<<<1, 512, 0, stream>>>(part, ht, scene, out_w, out_b, out, t);
    if (t < 63) {
      int tin = (t + 1 < 31) ? (t + 1) : 31;
      const float* op = others + (size_t)tin * 4096 * 2;
      update_kernel<<<8193, 256, 0, stream>>>(Z, op, target + (t + 1) * 2,
                                              w_ih, b_ih, b_hh, co, ct_t, ht, A, 1);
    }
  }
}

// Round 2
// 4938.506 us; speedup vs baseline: 1.0789x; 1.0789x over previous
//
#include <hip/hip_runtime.h>
#include <hip/hip_bf16.h>

// ---------------------------------------------------------------------------
// Sophie on MI355X, round 2.
// - No-LDS register GEMM (operands L2-resident; frags loaded global->VGPR).
// - Gate columns interleaved (col = 4*unit+gate) so the LSTM elementwise is
//   fused into the GEMM epilogue via 3 quad shuffles.
// - att + finalize fused via last-block atomic pattern.
// Per step: 2 kernel launches (gemm_fused, att_kernel).
// ---------------------------------------------------------------------------

typedef __bf16 bf16x8 __attribute__((ext_vector_type(8)));
typedef float  f32x4  __attribute__((ext_vector_type(4)));

#define NK 1536      // Z cols: k(0..511) | v(512..1023) | q(1024..1535)
#define KD 512

__device__ __forceinline__ float sigm(float x) {
  return __builtin_amdgcn_rcpf(1.f + __expf(-x));
}
__device__ __forceinline__ float tanh_f(float x) {
  return 2.f * __builtin_amdgcn_rcpf(1.f + __expf(-2.f * x)) - 1.f;
}
__device__ __forceinline__ float sel4(f32x4 v, int i) {
  float a = (i & 1) ? v[1] : v[0];
  float b = (i & 1) ? v[3] : v[2];
  return (i & 2) ? b : a;
}
__device__ __forceinline__ float pick(int m, float o0, float o1, float o2, float o3) {
  float a = (m & 1) ? o1 : o0;
  float b = (m & 1) ? o3 : o2;
  return (m & 2) ? b : a;
}

// ---------------------------------------------------------------------------
// GEMM + fused epilogues.
// A[4224][512] bf16 (rows: 4096 others, 1 target, 127 pad-garbage).
// Wp packed [ntg=224][kg=64][nn=16][j=8] bf16.
//   cols 0..2047   : gates interleaved (col = 4*unit + gate), epilogue = LSTM
//   cols 2048..3583: k|v|q -> Z fp32 with bias folded
// Grid 788: id<528 gate (bn=id/33, bm=id%33); 528..783 kv (bn=16+t/32, bm=t%32);
//           784..787 q (bm=32, bn=24+..).
// ---------------------------------------------------------------------------
__global__ __launch_bounds__(256) void gemm_fused(
    const unsigned short* __restrict__ A,
    const unsigned short* __restrict__ Wp,
    float* __restrict__ Z,
    const float* __restrict__ biasz,   // [1536] = bk|bv|bq
    const float4* __restrict__ bs4,    // [512] units: b_ih+b_hh, gate-interleaved
    const float4* __restrict__ w04,    // [512] w_ih[:,0]
    const float4* __restrict__ w14,    // [512] w_ih[:,1]
    const float* __restrict__ op,      // others[tin]: [4096][2]
    const float* __restrict__ tp,      // target[tc]: [2]
    float* __restrict__ co,            // [4097][512]
    __bf16* __restrict__ An,           // next-step A
    float* __restrict__ htn)           // next-step target h fp32 [512]
{
  const int tid = threadIdx.x, wave = tid >> 6, lane = tid & 63;
  const int wm = wave >> 1, wn = wave & 1;
  int id = blockIdx.x, bm, bn;
  if (id < 528)      { bn = id / 33;              bm = id % 33; }
  else if (id < 784) { int t2 = id - 528; bn = 16 + (t2 >> 5); bm = t2 & 31; }
  else               { bm = 32;                   bn = 24 + (id - 784); }
  const int m0 = bm * 128, n0 = bn * 128;
  const int l15 = lane & 15, lq = lane >> 4;

  const unsigned short* aBase = A + (size_t)(m0 + wm * 64 + l15) * KD + lq * 8;
  const unsigned short* bBase = Wp + (size_t)((n0 >> 4) + wn * 4) * 8192 + lq * 128 + l15 * 8;

  f32x4 acc[4][4];
#pragma unroll
  for (int i = 0; i < 4; ++i)
#pragma unroll
    for (int j = 0; j < 4; ++j) acc[i][j] = f32x4{0.f, 0.f, 0.f, 0.f};

  bf16x8 aC[4], bC[4], aN[4], bN[4];
#pragma unroll
  for (int mt = 0; mt < 4; ++mt) aC[mt] = *(const bf16x8*)(aBase + mt * 16 * KD);
#pragma unroll
  for (int nt = 0; nt < 4; ++nt) bC[nt] = *(const bf16x8*)(bBase + nt * 8192);

#pragma unroll
  for (int kk = 0; kk < 16; ++kk) {
    if (kk < 15) {
#pragma unroll
      for (int mt = 0; mt < 4; ++mt)
        aN[mt] = *(const bf16x8*)(aBase + mt * 16 * KD + (kk + 1) * 32);
#pragma unroll
      for (int nt = 0; nt < 4; ++nt)
        bN[nt] = *(const bf16x8*)(bBase + nt * 8192 + (kk + 1) * 512);
    }
#pragma unroll
    for (int mt = 0; mt < 4; ++mt)
#pragma unroll
      for (int nt = 0; nt < 4; ++nt)
        acc[mt][nt] = __builtin_amdgcn_mfma_f32_16x16x32_bf16(aC[mt], bC[nt], acc[mt][nt], 0, 0, 0);
    if (kk < 15) {
#pragma unroll
      for (int mt = 0; mt < 4; ++mt) aC[mt] = aN[mt];
#pragma unroll
      for (int nt = 0; nt < 4; ++nt) bC[nt] = bN[nt];
    }
  }

  const int rq = lq * 4;

  if (bn >= 16) {
    // ---- k/v/q epilogue: Z = acc + bias ----
    const int zb = n0 - 2048 + wn * 64;
    float bias[4];
#pragma unroll
    for (int nt = 0; nt < 4; ++nt) bias[nt] = biasz[zb + nt * 16 + l15];
#pragma unroll
    for (int mt = 0; mt < 4; ++mt) {
      int rowb = m0 + wm * 64 + mt * 16 + rq;
#pragma unroll
      for (int nt = 0; nt < 4; ++nt) {
        int col = zb + nt * 16 + l15;
#pragma unroll
        for (int r = 0; r < 4; ++r)
          Z[(size_t)(rowb + r) * NK + col] = acc[mt][nt][r] + bias[nt];
      }
    }
    return;
  }

  // ---- gate epilogue: fused LSTM cell ----
  const int rho = lane & 3, usel = (lane >> 2) & 3;
  const int u0 = (n0 >> 2) + wn * 16;
  float4 bsv[4], w0v[4], w1v[4];
  int uu[4];
#pragma unroll
  for (int nt = 0; nt < 4; ++nt) {
    uu[nt]  = u0 + nt * 4 + usel;
    bsv[nt] = bs4[uu[nt]];
    w0v[nt] = w04[uu[nt]];
    w1v[nt] = w14[uu[nt]];
  }
#pragma unroll
  for (int mt = 0; mt < 4; ++mt) {
    int row = m0 + wm * 64 + mt * 16 + rq + rho;
    bool act = row <= 4096;
    float x0 = 0.f, x1 = 0.f;
    if (act) {
      if (row < 4096) { x0 = op[2 * row]; x1 = op[2 * row + 1]; }
      else            { x0 = tp[0];       x1 = tp[1]; }
    }
#pragma unroll
    for (int nt = 0; nt < 4; ++nt) {
      f32x4 v = acc[mt][nt];
      // quad allgather: lane sends acc[(lane&3)^m], receives gate (rho^m) of row rho
      float own = sel4(v, rho);
      float r1  = __shfl_xor(sel4(v, rho ^ 1), 1, 64);
      float r2  = __shfl_xor(sel4(v, rho ^ 2), 2, 64);
      float r3  = __shfl_xor(sel4(v, rho ^ 3), 3, 64);
      float g0 = pick(rho,     own, r1, r2, r3);
      float g1 = pick(rho ^ 1, own, r1, r2, r3);
      float g2 = pick(rho ^ 2, own, r1, r2, r3);
      float g3 = pick(rho ^ 3, own, r1, r2, r3);
      if (act) {
        float4 bs = bsv[nt], w0 = w0v[nt], w1 = w1v[nt];
        float p0 = g0 + bs.x + w0.x * x0 + w1.x * x1;
        float p1 = g1 + bs.y + w0.y * x0 + w1.y * x1;
        float p2 = g2 + bs.z + w0.z * x0 + w1.z * x1;
        float p3 = g3 + bs.w + w0.w * x0 + w1.w * x1;
        int u = uu[nt];
        size_t ci = (size_t)row * 512 + u;
        float c_old = co[ci];
        float ii = sigm(p0), ff = sigm(p1), gg = tanh_f(p2), oo = sigm(p3);
        float cn = ff * c_old + ii * gg;
        float h  = oo * tanh_f(cn);
        co[ci] = cn;
        An[ci] = (__bf16)h;
        if (row == 4096) htn[u] = h;
      }
    }
  }
}

// ---------------------------------------------------------------------------
// Attention (64 blocks) + fused finalize (last-done block).
// k,v,q in Z are pre-biased. partial stride 513: [s0 x256 | s1 x256 | se].
// ---------------------------------------------------------------------------
__global__ __launch_bounds__(256) void att_kernel(
    const float* __restrict__ Z,
    const float* __restrict__ ht,      // current-step target h (fp32)
    const float* __restrict__ scene,
    const float* __restrict__ out_w,   // [2][512]
    const float* __restrict__ out_b,
    float* __restrict__ part,          // [64][513]
    unsigned int* __restrict__ cnt,
    float* __restrict__ out, int tstep)
{
  __shared__ __align__(16) float qs[512];
  __shared__ float red[256];
  __shared__ float red2[256];
  __shared__ float es[64];
  __shared__ unsigned int sOld;
  const int b = blockIdx.x, t = threadIdx.x;

  for (int c = t; c < 512; c += 256) qs[c] = Z[(size_t)4096 * NK + 1024 + c];
  __syncthreads();

  const int r0 = b * 64, rl = t >> 2, p = t & 3;
  const float4* krow = (const float4*)(Z + (size_t)(r0 + rl) * NK);
  const float4* qs4  = (const float4*)qs;
  float a = 0.f;
  for (int i = p; i < 128; i += 4) {
    float4 kk = krow[i], qq = qs4[i];
    a += kk.x * qq.x + kk.y * qq.y + kk.z * qq.z + kk.w * qq.w;
  }
  red[t] = a;
  __syncthreads();
  if (t < 64)
    es[t] = __expf((red[4 * t] + red[4 * t + 1] + red[4 * t + 2] + red[4 * t + 3]) *
                   0.04419417382415922f);
  __syncthreads();

  float s0 = 0.f, s1 = 0.f;
  for (int r = 0; r < 64; ++r) {
    const float* vr = Z + (size_t)(r0 + r) * NK + 512;
    float e = es[r];
    s0 += e * vr[t];
    s1 += e * vr[t + 256];
  }
  part[b * 513 + t] = s0;
  part[b * 513 + 256 + t] = s1;
  if (t == 0) {
    float se = 0.f;
    for (int r = 0; r < 64; ++r) se += es[r];
    part[b * 513 + 512] = se;
  }
  __threadfence();
  __syncthreads();
  if (t == 0) sOld = atomicAdd(cnt, 1u);
  __syncthreads();
  if (sOld == 63) {
    __threadfence();
    float s = 0.f, s2 = 0.f, se = 0.f;
    for (int bb = 0; bb < 64; ++bb) {
      s  += part[bb * 513 + t];
      s2 += part[bb * 513 + 256 + t];
      se += part[bb * 513 + 512];
    }
    float inv = 1.f / se;
    float va = ht[t] + s * inv + scene[t];
    float vb = ht[t + 256] + s2 * inv + scene[t + 256];
    red[t]  = va * out_w[t]       + vb * out_w[t + 256];
    red2[t] = va * out_w[512 + t] + vb * out_w[768 + t];
    __syncthreads();
    for (int st = 128; st > 0; st >>= 1) {
      if (t < st) { red[t] += red[t + st]; red2[t] += red2[t + st]; }
      __syncthreads();
    }
    if (t == 0) {
      out[2 * tstep]     = red[0]  + out_b[0];
      out[2 * tstep + 1] = red2[0] + out_b[1];
      *cnt = 0;
    }
  }
}

// ---------------------------------------------------------------------------
// Initial LSTM state (h,c from zero state, x at t=0) + counter init.
// ---------------------------------------------------------------------------
__global__ __launch_bounds__(256) void init_state(
    const float* __restrict__ others0, const float* __restrict__ target0,
    const float* __restrict__ w_ih, const float* __restrict__ b_ih,
    const float* __restrict__ b_hh,
    float* __restrict__ co, __bf16* __restrict__ A0, float* __restrict__ ht0,
    unsigned int* __restrict__ cnt)
{
  int g = blockIdx.x * 256 + threadIdx.x;
  if (g == 0) *cnt = 0u;
  if (g >= 4097 * 512) return;
  int r = g >> 9, j = g & 511;
  float x0, x1;
  if (r < 4096) { x0 = others0[2 * r]; x1 = others0[2 * r + 1]; }
  else          { x0 = target0[0];     x1 = target0[1]; }
  float pre[4];
#pragma unroll
  for (int gg = 0; gg < 4; ++gg) {
    int n = gg * 512 + j;
    pre[gg] = b_ih[n] + b_hh[n] + w_ih[2 * n] * x0 + w_ih[2 * n + 1] * x1;
  }
  float cn = sigm(pre[0]) * tanh_f(pre[2]);
  float h  = sigm(pre[3]) * tanh_f(cn);
  co[g] = cn;
  A0[g] = (__bf16)h;
  if (r == 4096) ht0[j] = h;
}

// ---------------------------------------------------------------------------
// Weight packing.
// ---------------------------------------------------------------------------
__global__ __launch_bounds__(256) void pack_w(
    const float* __restrict__ w_hh, const float* __restrict__ wk,
    const float* __restrict__ wv,   const float* __restrict__ wq,
    __bf16* __restrict__ Wp)
{
  int o = blockIdx.x * 256 + threadIdx.x;  // 224*64*16*8 = 1,835,008
  int j = o & 7, nn = (o >> 3) & 15, kg = (o >> 7) & 63, ntg = o >> 13;
  int n = ntg * 16 + nn, k = kg * 8 + j;
  float v;
  if (n < 2048)      { int u = n >> 2, g = n & 3; v = w_hh[(g * 512 + u) * 512 + k]; }
  else if (n < 2560) v = wk[(n - 2048) * 512 + k];
  else if (n < 3072) v = wv[(n - 2560) * 512 + k];
  else               v = wq[(n - 3072) * 512 + k];
  Wp[o] = (__bf16)v;
}

__global__ __launch_bounds__(256) void pack_misc(
    const float* __restrict__ b_ih, const float* __restrict__ b_hh,
    const float* __restrict__ w_ih,
    const float* __restrict__ bk, const float* __restrict__ bv,
    const float* __restrict__ bq,
    float* __restrict__ bs, float* __restrict__ w0, float* __restrict__ w1,
    float* __restrict__ biasz)
{
  int i = blockIdx.x * 256 + threadIdx.x;
  if (i < 2048) {
    int u = i >> 2, g = i & 3, n = g * 512 + u;
    bs[i] = b_ih[n] + b_hh[n];
    w0[i] = w_ih[2 * n];
    w1[i] = w_ih[2 * n + 1];
  } else if (i < 2048 + 1536) {
    int z = i - 2048;
    biasz[z] = (z < 512) ? bk[z] : (z < 1024 ? bv[z - 512] : bq[z - 1024]);
  }
}

// ---------------------------------------------------------------------------
// Scene CNN (unchanged from R1 — passed, runs once).
// ---------------------------------------------------------------------------
__global__ __launch_bounds__(256) void scene1_kernel(
    const int* __restrict__ map, const float* __restrict__ emb,
    const float* __restrict__ w1, const float* __restrict__ b1,
    float* __restrict__ out1)
{
  __shared__ float wl[576];
  __shared__ float bl[16];
  const int t = threadIdx.x;
  for (int i = t; i < 576; i += 256) wl[i] = w1[i];
  if (t < 16) bl[t] = b1[t];
  __syncthreads();
  const int y = blockIdx.x, x = t;
  float nb[4][9];
#pragma unroll
  for (int dy = 0; dy < 3; ++dy)
#pragma unroll
    for (int dx = 0; dx < 3; ++dx) {
      int yy = y + dy - 1, xx = x + dx - 1;
      bool ok = (yy >= 0 && yy < 256 && xx >= 0 && xx < 256);
      int m = ok ? map[yy * 256 + xx] : 0;
#pragma unroll
      for (int c = 0; c < 4; ++c)
        nb[c][dy * 3 + dx] = ok ? emb[m * 4 + c] : 0.f;
    }
  for (int oc = 0; oc < 16; ++oc) {
    float a = bl[oc];
#pragma unroll
    for (int c = 0; c < 4; ++c)
#pragma unroll
      for (int k = 0; k < 9; ++k) a += wl[(oc * 4 + c) * 9 + k] * nb[c][k];
    out1[oc * 65536 + y * 256 + x] = fmaxf(a, 0.f);
  }
}

__global__ __launch_bounds__(256) void scene2_kernel(
    const float* __restrict__ out1, const float* __restrict__ w2,
    const float* __restrict__ b2, float* __restrict__ rowpart)
{
  __shared__ float wl[4608];
  __shared__ float lds4[4 * 32];
  const int t = threadIdx.x;
  for (int i = t; i < 4608; i += 256) wl[i] = w2[i];
  __syncthreads();
  const int y = blockIdx.x, x = t;
  float acc[32];
#pragma unroll
  for (int oc = 0; oc < 32; ++oc) acc[oc] = b2[oc];
  for (int ic = 0; ic < 16; ++ic) {
    float nb[9];
#pragma unroll
    for (int dy = 0; dy < 3; ++dy)
#pragma unroll
      for (int dx = 0; dx < 3; ++dx) {
        int yy = y + dy - 1, xx = x + dx - 1;
        bool ok = (yy >= 0 && yy < 256 && xx >= 0 && xx < 256);
        nb[dy * 3 + dx] = ok ? out1[ic * 65536 + yy * 256 + xx] : 0.f;
      }
    for (int oc = 0; oc < 32; ++oc) {
      const float* w = &wl[(oc * 16 + ic) * 9];
#pragma unroll
      for (int k = 0; k < 9; ++k) acc[oc] += w[k] * nb[k];
    }
  }
  const int wave = t >> 6, lane = t & 63;
  for (int oc = 0; oc < 32; ++oc) {
    float v = fmaxf(acc[oc], 0.f);
#pragma unroll
    for (int m = 1; m < 64; m <<= 1) v += __shfl_xor(v, m, 64);
    if (lane == 0) lds4[wave * 32 + oc] = v;
  }
  __syncthreads();
  if (t < 32)
    rowpart[y * 32 + t] = lds4[t] + lds4[32 + t] + lds4[64 + t] + lds4[96 + t];
}

__global__ __launch_bounds__(512) void scene3_kernel(
    const float* __restrict__ rowpart, const float* __restrict__ fcw,
    const float* __restrict__ fcb, float* __restrict__ scene)
{
  __shared__ float mean[32];
  const int t = threadIdx.x;
  if (t < 32) {
    float s = 0.f;
    for (int y = 0; y < 256; ++y) s += rowpart[y * 32 + t];
    mean[t] = s * (1.f / 65536.f);
  }
  __syncthreads();
  float a = fcb[t];
#pragma unroll
  for (int c = 0; c < 32; ++c) a += mean[c] * fcw[t * 32 + c];
  scene[t] = a;
}

// ---------------------------------------------------------------------------
extern "C" void kernel_launch(void* const* d_in, const int* in_sizes, int n_in,
                              void* d_out, int out_size, void* d_ws, size_t ws_size,
                              hipStream_t stream) {
  const float* target    = (const float*)d_in[0];
  const float* others    = (const float*)d_in[1];
  const int*   scene_map = (const int*)d_in[2];
  const float* emb       = (const float*)d_in[3];
  const float* c1w       = (const float*)d_in[4];
  const float* c1b       = (const float*)d_in[5];
  const float* c2w       = (const float*)d_in[6];
  const float* c2b       = (const float*)d_in[7];
  const float* fcw       = (const float*)d_in[8];
  const float* fcb       = (const float*)d_in[9];
  const float* w_ih      = (const float*)d_in[10];
  const float* w_hh      = (const float*)d_in[11];
  const float* b_ih      = (const float*)d_in[12];
  const float* b_hh      = (const float*)d_in[13];
  const float* wq        = (const float*)d_in[14];
  const float* bq        = (const float*)d_in[15];
  const float* wk        = (const float*)d_in[16];
  const float* bk        = (const float*)d_in[17];
  const float* wv        = (const float*)d_in[18];
  const float* bv        = (const float*)d_in[19];
  const float* out_w     = (const float*)d_in[20];
  const float* out_b     = (const float*)d_in[21];
  float* out = (float*)d_out;

  char* ws = (char*)d_ws;
  size_t off = 0;
  auto alloc = [&](size_t bytes) { size_t o = off; off += (bytes + 255) & ~(size_t)255; return o; };
  float*  Z     = (float*)(ws + alloc((size_t)4224 * NK * 4));    // 25.95 MB
  __bf16* Wp    = (__bf16*)(ws + alloc((size_t)1835008 * 2));     // 3.67 MB
  __bf16* A0    = (__bf16*)(ws + alloc((size_t)4224 * 512 * 2));  // 4.33 MB
  __bf16* A1    = (__bf16*)(ws + alloc((size_t)4224 * 512 * 2));  // 4.33 MB
  float*  co    = (float*)(ws + alloc((size_t)4097 * 512 * 4));   // 8.39 MB
  float*  ht0   = (float*)(ws + alloc(2048));
  float*  ht1   = (float*)(ws + alloc(2048));
  float*  scene = (float*)(ws + alloc(2048));
  float*  part  = (float*)(ws + alloc(64 * 513 * 4));
  unsigned int* cnt = (unsigned int*)(ws + alloc(256));
  float*  bs    = (float*)(ws + alloc(2048 * 4));
  float*  w0p   = (float*)(ws + alloc(2048 * 4));
  float*  w1p   = (float*)(ws + alloc(2048 * 4));
  float*  biasz = (float*)(ws + alloc(1536 * 4));
  float*  out1  = (float*)(ws + alloc((size_t)16 * 65536 * 4));   // 4.19 MB
  float*  rowp  = (float*)(ws + alloc(256 * 32 * 4));

  // one-time prep
  pack_w<<<7168, 256, 0, stream>>>(w_hh, wk, wv, wq, Wp);
  pack_misc<<<14, 256, 0, stream>>>(b_ih, b_hh, w_ih, bk, bv, bq, bs, w0p, w1p, biasz);
  scene1_kernel<<<256, 256, 0, stream>>>(scene_map, emb, c1w, c1b, out1);
  scene2_kernel<<<256, 256, 0, stream>>>(out1, c2w, c2b, rowp);
  scene3_kernel<<<1, 512, 0, stream>>>(rowp, fcw, fcb, scene);
  init_state<<<8194, 256, 0, stream>>>(others, target, w_ih, b_ih, b_hh, co, A0, ht0, cnt);

  __bf16* Ab[2]  = {A0, A1};
  float*  htb[2] = {ht0, ht1};

  for (int t = 0; t < 64; ++t) {
    int tin = (t + 1 < 31) ? (t + 1) : 31;
    int tc  = (t + 1 < 63) ? (t + 1) : 63;
    gemm_fused<<<788, 256, 0, stream>>>(
        (const unsigned short*)Ab[t & 1], (const unsigned short*)Wp, Z, biasz,
        (const float4*)bs, (const float4*)w0p, (const float4*)w1p,
        others + (size_t)tin * 4096 * 2, target + tc * 2,
        co, Ab[(t + 1) & 1], htb[(t + 1) & 1]);
    att_kernel<<<64, 256, 0, stream>>>(Z, htb[t & 1], scene, out_w, out_b,
                                       part, cnt, out, t);
  }
}

// Round 3
// 4032.581 us; speedup vs baseline: 1.3213x; 1.2247x over previous
//
#include <hip/hip_runtime.h>
#include <hip/hip_bf16.h>

// ---------------------------------------------------------------------------
// Sophie on MI355X, round 3.
// GEMM v3: A staged in LDS (shared by all 4 waves, xor-swizzled, double-
// buffered, global_load_lds 16B), B loaded global->reg (coalesced 1KB/inst),
// per-wave 128x32 output strip => zero redundant operand traffic.
// LSTM fused in gate epilogue; att(128 blocks)+finalize fused via atomic.
// ---------------------------------------------------------------------------

typedef __bf16 bf16x8 __attribute__((ext_vector_type(8)));
typedef float  f32x4  __attribute__((ext_vector_type(4)));

#define NK 1536      // Z cols: k(0..511) | v(512..1023) | q(1024..1535)
#define KD 512

__device__ __forceinline__ void gl_lds16(const void* g, void* l) {
  __builtin_amdgcn_global_load_lds(
      (const __attribute__((address_space(1))) void*)g,
      (__attribute__((address_space(3))) void*)l, 16, 0, 0);
}
__device__ __forceinline__ float sigm(float x) {
  return __builtin_amdgcn_rcpf(1.f + __expf(-x));
}
__device__ __forceinline__ float tanh_f(float x) {
  return 2.f * __builtin_amdgcn_rcpf(1.f + __expf(-2.f * x)) - 1.f;
}
__device__ __forceinline__ float sel4(f32x4 v, int i) {
  float a = (i & 1) ? v[1] : v[0];
  float b = (i & 1) ? v[3] : v[2];
  return (i & 2) ? b : a;
}
__device__ __forceinline__ float pick(int m, float o0, float o1, float o2, float o3) {
  float a = (m & 1) ? o1 : o0;
  float b = (m & 1) ? o3 : o2;
  return (m & 2) ? b : a;
}

// ---------------------------------------------------------------------------
// GEMM + fused epilogues. Grid 788 as before.
// Wave w computes cols [n0+32w, n0+32w+32), all 128 rows (mt 0..7, nt 0..1).
// ---------------------------------------------------------------------------
__global__ __launch_bounds__(256) void gemm_fused(
    const unsigned short* __restrict__ A,
    const unsigned short* __restrict__ Wp,
    float* __restrict__ Z,
    const float* __restrict__ biasz,   // [1536] = bk|bv|bq
    const float4* __restrict__ bs4,    // [512] units: b_ih+b_hh gate-interleaved
    const float4* __restrict__ w04,
    const float4* __restrict__ w14,
    const float* __restrict__ op,      // others[tin]: [4096][2]
    const float* __restrict__ tp,      // target[tc]: [2]
    float* __restrict__ co,            // [4097][512]
    __bf16* __restrict__ An,
    float* __restrict__ htn)
{
  __shared__ __align__(16) char aLds[2][128 * 64 * 2];   // 2 x 16 KB

  const int tid = threadIdx.x, wave = tid >> 6, lane = tid & 63;
  int id = blockIdx.x, bm, bn;
  if (id < 528)      { bn = id / 33;              bm = id % 33; }
  else if (id < 784) { int t2 = id - 528; bn = 16 + (t2 >> 5); bm = t2 & 31; }
  else               { bm = 32;                   bn = 24 + (id - 784); }
  const int m0 = bm * 128, n0 = bn * 128;
  const int l15 = lane & 15, lq = lane >> 4;

  // A staging descriptors: 16 chunks of 1KB; chunk = j*4 + wave.
  int aRow[4], aOff[4], ldsOff[4];
#pragma unroll
  for (int j = 0; j < 4; ++j) {
    int chunk = j * 4 + wave;
    int r = chunk * 8 + (lane >> 3), ch = lane & 7;
    aRow[j]   = m0 + r;
    aOff[j]   = (ch ^ (r & 7)) * 8;
    ldsOff[j] = chunk * 1024;
  }

  // B base for this wave: ntg = n0/16 + 2*wave (+nt)
  const unsigned short* bBase =
      Wp + (size_t)((n0 >> 4) + 2 * wave) * 8192 + lq * 128 + l15 * 8;

  f32x4 acc[8][2];
#pragma unroll
  for (int i = 0; i < 8; ++i) { acc[i][0] = f32x4{0,0,0,0}; acc[i][1] = f32x4{0,0,0,0}; }

  bf16x8 bC[2][2], bN[2][2];   // [c][nt]

  // prologue: stage iter0
#pragma unroll
  for (int j = 0; j < 4; ++j)
    gl_lds16(A + (size_t)aRow[j] * KD + aOff[j], aLds[0] + ldsOff[j]);
#pragma unroll
  for (int c = 0; c < 2; ++c)
#pragma unroll
    for (int nt = 0; nt < 2; ++nt)
      bC[c][nt] = *(const bf16x8*)(bBase + nt * 8192 + c * 512);
  __syncthreads();

#pragma unroll 2
  for (int it = 0; it < 8; ++it) {
    const char* buf = aLds[it & 1];
    if (it < 7) {
      const int k1 = (it + 1) * 64;
#pragma unroll
      for (int j = 0; j < 4; ++j)
        gl_lds16(A + (size_t)aRow[j] * KD + k1 + aOff[j], aLds[(it + 1) & 1] + ldsOff[j]);
#pragma unroll
      for (int c = 0; c < 2; ++c)
#pragma unroll
        for (int nt = 0; nt < 2; ++nt)
          bN[c][nt] = *(const bf16x8*)(bBase + nt * 8192 + (it + 1) * 1024 + c * 512);
    }
#pragma unroll
    for (int c = 0; c < 2; ++c) {
      bf16x8 af[8];
#pragma unroll
      for (int mt = 0; mt < 8; ++mt) {
        int row = mt * 16 + l15;
        int ch16 = (c * 4 + lq) ^ (row & 7);
        af[mt] = *(const bf16x8*)(buf + row * 128 + ch16 * 16);
      }
#pragma unroll
      for (int mt = 0; mt < 8; ++mt)
#pragma unroll
        for (int nt = 0; nt < 2; ++nt)
          acc[mt][nt] = __builtin_amdgcn_mfma_f32_16x16x32_bf16(
              af[mt], bC[c][nt], acc[mt][nt], 0, 0, 0);
    }
    if (it < 7) {
#pragma unroll
      for (int c = 0; c < 2; ++c)
#pragma unroll
        for (int nt = 0; nt < 2; ++nt) bC[c][nt] = bN[c][nt];
    }
    __syncthreads();
  }

  const int rq = lq * 4;

  if (bn >= 16) {
    // ---- k/v/q epilogue ----
    const int zb = n0 - 2048 + wave * 32;
    float bias[2];
#pragma unroll
    for (int nt = 0; nt < 2; ++nt) bias[nt] = biasz[zb + nt * 16 + l15];
#pragma unroll
    for (int mt = 0; mt < 8; ++mt) {
      int rowb = m0 + mt * 16 + rq;
#pragma unroll
      for (int nt = 0; nt < 2; ++nt) {
        int col = zb + nt * 16 + l15;
#pragma unroll
        for (int r = 0; r < 4; ++r)
          Z[(size_t)(rowb + r) * NK + col] = acc[mt][nt][r] + bias[nt];
      }
    }
    return;
  }

  // ---- gate epilogue: fused LSTM cell ----
  const int rho = lane & 3, usel = (lane >> 2) & 3;
  const int u0 = (n0 >> 2) + wave * 8;
  float4 bsv[2], w0v[2], w1v[2];
  int uu[2];
#pragma unroll
  for (int nt = 0; nt < 2; ++nt) {
    uu[nt]  = u0 + nt * 4 + usel;
    bsv[nt] = bs4[uu[nt]];
    w0v[nt] = w04[uu[nt]];
    w1v[nt] = w14[uu[nt]];
  }
#pragma unroll
  for (int mt = 0; mt < 8; ++mt) {
    int row = m0 + mt * 16 + rq + rho;
    bool act = row <= 4096;
    float x0 = 0.f, x1 = 0.f;
    if (act) {
      if (row < 4096) { x0 = op[2 * row]; x1 = op[2 * row + 1]; }
      else            { x0 = tp[0];       x1 = tp[1]; }
    }
#pragma unroll
    for (int nt = 0; nt < 2; ++nt) {
      f32x4 v = acc[mt][nt];
      float own = sel4(v, rho);
      float r1  = __shfl_xor(sel4(v, rho ^ 1), 1, 64);
      float r2  = __shfl_xor(sel4(v, rho ^ 2), 2, 64);
      float r3  = __shfl_xor(sel4(v, rho ^ 3), 3, 64);
      float g0 = pick(rho,     own, r1, r2, r3);
      float g1 = pick(rho ^ 1, own, r1, r2, r3);
      float g2 = pick(rho ^ 2, own, r1, r2, r3);
      float g3 = pick(rho ^ 3, own, r1, r2, r3);
      if (act) {
        float4 bs = bsv[nt], w0 = w0v[nt], w1 = w1v[nt];
        float p0 = g0 + bs.x + w0.x * x0 + w1.x * x1;
        float p1 = g1 + bs.y + w0.y * x0 + w1.y * x1;
        float p2 = g2 + bs.z + w0.z * x0 + w1.z * x1;
        float p3 = g3 + bs.w + w0.w * x0 + w1.w * x1;
        int u = uu[nt];
        size_t ci = (size_t)row * 512 + u;
        float c_old = co[ci];
        float ii = sigm(p0), ff = sigm(p1), gg = tanh_f(p2), oo = sigm(p3);
        float cn = ff * c_old + ii * gg;
        float h  = oo * tanh_f(cn);
        co[ci] = cn;
        An[ci] = (__bf16)h;
        if (row == 4096) htn[u] = h;
      }
    }
  }
}

// ---------------------------------------------------------------------------
// Attention: 128 blocks x 32 rows, + fused finalize in last-done block.
// ---------------------------------------------------------------------------
__global__ __launch_bounds__(256) void att_kernel(
    const float* __restrict__ Z,
    const float* __restrict__ ht,
    const float* __restrict__ scene,
    const float* __restrict__ out_w,
    const float* __restrict__ out_b,
    float* __restrict__ part,          // [128][513]
    unsigned int* __restrict__ cnt,
    float* __restrict__ out, int tstep)
{
  __shared__ __align__(16) float qs[512];
  __shared__ float red[256];
  __shared__ float red2[256];
  __shared__ float es[32];
  __shared__ unsigned int sOld;
  const int b = blockIdx.x, t = threadIdx.x;

  for (int c = t; c < 512; c += 256) qs[c] = Z[(size_t)4096 * NK + 1024 + c];
  __syncthreads();

  const int r0 = b * 32, rl = t >> 3, p = t & 7;
  const float4* krow = (const float4*)(Z + (size_t)(r0 + rl) * NK);
  const float4* qs4  = (const float4*)qs;
  float a = 0.f;
  for (int i = p; i < 128; i += 8) {
    float4 kk = krow[i], qq = qs4[i];
    a += kk.x * qq.x + kk.y * qq.y + kk.z * qq.z + kk.w * qq.w;
  }
  red[t] = a;
  __syncthreads();
  if (t < 32) {
    float l = 0.f;
#pragma unroll
    for (int j = 0; j < 8; ++j) l += red[8 * t + j];
    es[t] = __expf(l * 0.04419417382415922f);
  }
  __syncthreads();

  float s0 = 0.f, s1 = 0.f;
  for (int r = 0; r < 32; ++r) {
    const float* vr = Z + (size_t)(r0 + r) * NK + 512;
    float e = es[r];
    s0 += e * vr[t];
    s1 += e * vr[t + 256];
  }
  part[b * 513 + t] = s0;
  part[b * 513 + 256 + t] = s1;
  if (t == 0) {
    float se = 0.f;
#pragma unroll
    for (int r = 0; r < 32; ++r) se += es[r];
    part[b * 513 + 512] = se;
  }
  __threadfence();
  __syncthreads();
  if (t == 0) sOld = atomicAdd(cnt, 1u);
  __syncthreads();
  if (sOld == 127) {
    __threadfence();
    float s = 0.f, s2 = 0.f, se = 0.f;
    for (int bb = 0; bb < 128; ++bb) {
      s  += part[bb * 513 + t];
      s2 += part[bb * 513 + 256 + t];
      se += part[bb * 513 + 512];
    }
    float inv = 1.f / se;
    float va = ht[t] + s * inv + scene[t];
    float vb = ht[t + 256] + s2 * inv + scene[t + 256];
    red[t]  = va * out_w[t]       + vb * out_w[t + 256];
    red2[t] = va * out_w[512 + t] + vb * out_w[768 + t];
    __syncthreads();
    for (int st = 128; st > 0; st >>= 1) {
      if (t < st) { red[t] += red[t + st]; red2[t] += red2[t + st]; }
      __syncthreads();
    }
    if (t == 0) {
      out[2 * tstep]     = red[0]  + out_b[0];
      out[2 * tstep + 1] = red2[0] + out_b[1];
      *cnt = 0;
    }
  }
}

// ---------------------------------------------------------------------------
__global__ __launch_bounds__(256) void init_state(
    const float* __restrict__ others0, const float* __restrict__ target0,
    const float* __restrict__ w_ih, const float* __restrict__ b_ih,
    const float* __restrict__ b_hh,
    float* __restrict__ co, __bf16* __restrict__ A0, float* __restrict__ ht0,
    unsigned int* __restrict__ cnt)
{
  int g = blockIdx.x * 256 + threadIdx.x;
  if (g == 0) *cnt = 0u;
  if (g >= 4097 * 512) return;
  int r = g >> 9, j = g & 511;
  float x0, x1;
  if (r < 4096) { x0 = others0[2 * r]; x1 = others0[2 * r + 1]; }
  else          { x0 = target0[0];     x1 = target0[1]; }
  float pre[4];
#pragma unroll
  for (int gg = 0; gg < 4; ++gg) {
    int n = gg * 512 + j;
    pre[gg] = b_ih[n] + b_hh[n] + w_ih[2 * n] * x0 + w_ih[2 * n + 1] * x1;
  }
  float cn = sigm(pre[0]) * tanh_f(pre[2]);
  float h  = sigm(pre[3]) * tanh_f(cn);
  co[g] = cn;
  A0[g] = (__bf16)h;
  if (r == 4096) ht0[j] = h;
}

// ---------------------------------------------------------------------------
__global__ __launch_bounds__(256) void pack_w(
    const float* __restrict__ w_hh, const float* __restrict__ wk,
    const float* __restrict__ wv,   const float* __restrict__ wq,
    __bf16* __restrict__ Wp)
{
  int o = blockIdx.x * 256 + threadIdx.x;  // 1,835,008
  int j = o & 7, nn = (o >> 3) & 15, kg = (o >> 7) & 63, ntg = o >> 13;
  int n = ntg * 16 + nn, k = kg * 8 + j;
  float v;
  if (n < 2048)      { int u = n >> 2, g = n & 3; v = w_hh[(g * 512 + u) * 512 + k]; }
  else if (n < 2560) v = wk[(n - 2048) * 512 + k];
  else if (n < 3072) v = wv[(n - 2560) * 512 + k];
  else               v = wq[(n - 3072) * 512 + k];
  Wp[o] = (__bf16)v;
}

__global__ __launch_bounds__(256) void pack_misc(
    const float* __restrict__ b_ih, const float* __restrict__ b_hh,
    const float* __restrict__ w_ih,
    const float* __restrict__ bk, const float* __restrict__ bv,
    const float* __restrict__ bq,
    float* __restrict__ bs, float* __restrict__ w0, float* __restrict__ w1,
    float* __restrict__ biasz)
{
  int i = blockIdx.x * 256 + threadIdx.x;
  if (i < 2048) {
    int u = i >> 2, g = i & 3, n = g * 512 + u;
    bs[i] = b_ih[n] + b_hh[n];
    w0[i] = w_ih[2 * n];
    w1[i] = w_ih[2 * n + 1];
  } else if (i < 2048 + 1536) {
    int z = i - 2048;
    biasz[z] = (z < 512) ? bk[z] : (z < 1024 ? bv[z - 512] : bq[z - 1024]);
  }
}

// ---------------------------------------------------------------------------
// Scene CNN.
// ---------------------------------------------------------------------------
__global__ __launch_bounds__(256) void scene1_kernel(
    const int* __restrict__ map, const float* __restrict__ emb,
    const float* __restrict__ w1, const float* __restrict__ b1,
    float* __restrict__ out1)
{
  __shared__ float wl[576];
  __shared__ float bl[16];
  const int t = threadIdx.x;
  for (int i = t; i < 576; i += 256) wl[i] = w1[i];
  if (t < 16) bl[t] = b1[t];
  __syncthreads();
  const int y = blockIdx.x, x = t;
  float nb[4][9];
#pragma unroll
  for (int dy = 0; dy < 3; ++dy)
#pragma unroll
    for (int dx = 0; dx < 3; ++dx) {
      int yy = y + dy - 1, xx = x + dx - 1;
      bool ok = (yy >= 0 && yy < 256 && xx >= 0 && xx < 256);
      int m = ok ? map[yy * 256 + xx] : 0;
#pragma unroll
      for (int c = 0; c < 4; ++c)
        nb[c][dy * 3 + dx] = ok ? emb[m * 4 + c] : 0.f;
    }
  for (int oc = 0; oc < 16; ++oc) {
    float a = bl[oc];
#pragma unroll
    for (int c = 0; c < 4; ++c)
#pragma unroll
      for (int k = 0; k < 9; ++k) a += wl[(oc * 4 + c) * 9 + k] * nb[c][k];
    out1[oc * 65536 + y * 256 + x] = fmaxf(a, 0.f);
  }
}

// 1024 blocks: y = blk & 255, oc-group = blk >> 8 (8 oc each).
__global__ __launch_bounds__(256) void scene2_kernel(
    const float* __restrict__ out1, const float* __restrict__ w2,
    const float* __restrict__ b2, float* __restrict__ rowpart)  // [256][32]
{
  __shared__ float wl[1152];
  __shared__ float lds4[4 * 8];
  const int t = threadIdx.x;
  const int y = blockIdx.x & 255, ocg = blockIdx.x >> 8;
  for (int i = t; i < 1152; i += 256) wl[i] = w2[ocg * 1152 + i];
  __syncthreads();
  const int x = t;
  float acc[8];
#pragma unroll
  for (int o = 0; o < 8; ++o) acc[o] = b2[ocg * 8 + o];
  for (int ic = 0; ic < 16; ++ic) {
    float nb[9];
#pragma unroll
    for (int dy = 0; dy < 3; ++dy)
#pragma unroll
      for (int dx = 0; dx < 3; ++dx) {
        int yy = y + dy - 1, xx = x + dx - 1;
        bool ok = (yy >= 0 && yy < 256 && xx >= 0 && xx < 256);
        nb[dy * 3 + dx] = ok ? out1[ic * 65536 + yy * 256 + xx] : 0.f;
      }
#pragma unroll
    for (int o = 0; o < 8; ++o) {
      const float* w = &wl[(o * 16 + ic) * 9];
#pragma unroll
      for (int k = 0; k < 9; ++k) acc[o] += w[k] * nb[k];
    }
  }
  const int wave = t >> 6, lane = t & 63;
#pragma unroll
  for (int o = 0; o < 8; ++o) {
    float v = fmaxf(acc[o], 0.f);
#pragma unroll
    for (int m = 1; m < 64; m <<= 1) v += __shfl_xor(v, m, 64);
    if (lane == 0) lds4[wave * 8 + o] = v;
  }
  __syncthreads();
  if (t < 8)
    rowpart[y * 32 + ocg * 8 + t] = lds4[t] + lds4[8 + t] + lds4[16 + t] + lds4[24 + t];
}

__global__ __launch_bounds__(512) void scene3_kernel(
    const float* __restrict__ rowpart, const float* __restrict__ fcw,
    const float* __restrict__ fcb, float* __restrict__ scene)
{
  __shared__ float mean[32];
  const int t = threadIdx.x;
  if (t < 32) {
    float s = 0.f;
    for (int y = 0; y < 256; ++y) s += rowpart[y * 32 + t];
    mean[t] = s * (1.f / 65536.f);
  }
  __syncthreads();
  float a = fcb[t];
#pragma unroll
  for (int c = 0; c < 32; ++c) a += mean[c] * fcw[t * 32 + c];
  scene[t] = a;
}

// ---------------------------------------------------------------------------
extern "C" void kernel_launch(void* const* d_in, const int* in_sizes, int n_in,
                              void* d_out, int out_size, void* d_ws, size_t ws_size,
                              hipStream_t stream) {
  const float* target    = (const float*)d_in[0];
  const float* others    = (const float*)d_in[1];
  const int*   scene_map = (const int*)d_in[2];
  const float* emb       = (const float*)d_in[3];
  const float* c1w       = (const float*)d_in[4];
  const float* c1b       = (const float*)d_in[5];
  const float* c2w       = (const float*)d_in[6];
  const float* c2b       = (const float*)d_in[7];
  const float* fcw       = (const float*)d_in[8];
  const float* fcb       = (const float*)d_in[9];
  const float* w_ih      = (const float*)d_in[10];
  const float* w_hh      = (const float*)d_in[11];
  const float* b_ih      = (const float*)d_in[12];
  const float* b_hh      = (const float*)d_in[13];
  const float* wq        = (const float*)d_in[14];
  const float* bq        = (const float*)d_in[15];
  const float* wk        = (const float*)d_in[16];
  const float* bk        = (const float*)d_in[17];
  const float* wv        = (const float*)d_in[18];
  const float* bv        = (const float*)d_in[19];
  const float* out_w     = (const float*)d_in[20];
  const float* out_b     = (const float*)d_in[21];
  float* out = (float*)d_out;

  char* ws = (char*)d_ws;
  size_t off = 0;
  auto alloc = [&](size_t bytes) { size_t o = off; off += (bytes + 255) & ~(size_t)255; return o; };
  float*  Z     = (float*)(ws + alloc((size_t)4224 * NK * 4));
  __bf16* Wp    = (__bf16*)(ws + alloc((size_t)1835008 * 2));
  __bf16* A0    = (__bf16*)(ws + alloc((size_t)4224 * 512 * 2));
  __bf16* A1    = (__bf16*)(ws + alloc((size_t)4224 * 512 * 2));
  float*  co    = (float*)(ws + alloc((size_t)4097 * 512 * 4));
  float*  ht0   = (float*)(ws + alloc(2048));
  float*  ht1   = (float*)(ws + alloc(2048));
  float*  scene = (float*)(ws + alloc(2048));
  float*  part  = (float*)(ws + alloc(128 * 513 * 4));
  unsigned int* cnt = (unsigned int*)(ws + alloc(256));
  float*  bs    = (float*)(ws + alloc(2048 * 4));
  float*  w0p   = (float*)(ws + alloc(2048 * 4));
  float*  w1p   = (float*)(ws + alloc(2048 * 4));
  float*  biasz = (float*)(ws + alloc(1536 * 4));
  float*  out1  = (float*)(ws + alloc((size_t)16 * 65536 * 4));
  float*  rowp  = (float*)(ws + alloc(256 * 32 * 4));

  pack_w<<<7168, 256, 0, stream>>>(w_hh, wk, wv, wq, Wp);
  pack_misc<<<14, 256, 0, stream>>>(b_ih, b_hh, w_ih, bk, bv, bq, bs, w0p, w1p, biasz);
  scene1_kernel<<<256, 256, 0, stream>>>(scene_map, emb, c1w, c1b, out1);
  scene2_kernel<<<1024, 256, 0, stream>>>(out1, c2w, c2b, rowp);
  scene3_kernel<<<1, 512, 0, stream>>>(rowp, fcw, fcb, scene);
  init_state<<<8194, 256, 0, stream>>>(others, target, w_ih, b_ih, b_hh, co, A0, ht0, cnt);

  __bf16* Ab[2]  = {A0, A1};
  float*  htb[2] = {ht0, ht1};

  for (int t = 0; t < 64; ++t) {
    int tin = (t + 1 < 31) ? (t + 1) : 31;
    int tc  = (t + 1 < 63) ? (t + 1) : 63;
    gemm_fused<<<788, 256, 0, stream>>>(
        (const unsigned short*)Ab[t & 1], (const unsigned short*)Wp, Z, biasz,
        (const float4*)bs, (const float4*)w0p, (const float4*)w1p,
        others + (size_t)tin * 4096 * 2, target + tc * 2,
        co, Ab[(t + 1) & 1], htb[(t + 1) & 1]);
    att_kernel<<<128, 256, 0, stream>>>(Z, htb[t & 1], scene, out_w, out_b,
                                        part, cnt, out, t);
  }
}